// Round 15
// baseline (171.398 us; speedup 1.0000x reference)
//
#include <hip/hip_runtime.h>
#include <hip/hip_bf16.h>

// Problem constants
#define BB 2
#define SS 2048
#define CC 1024
#define HH 16
#define DDIM 64
#define NROWS (BB*SS)   // 4096

// q pre-scale: (1/sqrt(64)) / ln2  -> scores in log2 units, exp2 == exp
#define QSC 0.18033688011112042f

typedef __attribute__((ext_vector_type(8))) short bf16x8;   // 8 bf16 = 4 VGPR
typedef __attribute__((ext_vector_type(4))) float f32x4;

__device__ __forceinline__ f32x4 mfma16(bf16x8 a, bf16x8 b, f32x4 c) {
    return __builtin_amdgcn_mfma_f32_16x16x32_bf16(a, b, c, 0, 0, 0);
}

// ---------------------------------------------------------------------------
// MFMA grouped projection v4: prep_wt FUSED IN (R12: top-5 = harness fill
// kernels; per-dispatch machinery is the unaccounted time -> cut dispatch
// count 4->2). Per kt, each block stages its own W^T tile: fp32 [64k][128n]
// coalesced load -> bf16 transpose into LDS Ws[128][72] (prep_wt's verified
// write pattern). W is 12MB fp32, L2/L3-resident; 32x re-read is ~free.
// A-fragments stay direct-from-global (v3, verified: wave-private rows).
// 2 barriers per kt; LDS 18.4KB main loop, epilogue reuses (<=36.9KB).
// Removes: prep dispatch + boundary, wt workspace roundtrip.
// grid (32, 8, 3) = 768 blocks.
// ---------------------------------------------------------------------------
__global__ __launch_bounds__(256, 2) void proj_mfma(
    const float* __restrict__ qin, const float* __restrict__ kin,
    const float* __restrict__ vin,
    const float* __restrict__ wq, const float* __restrict__ wk,
    const float* __restrict__ wv,
    const float* __restrict__ bq, const float* __restrict__ bk,
    const float* __restrict__ bv,
    __hip_bfloat16* __restrict__ qs, __hip_bfloat16* __restrict__ ks_,
    __hip_bfloat16* __restrict__ vs)
{
    const int z = blockIdx.z;
    const float* src; const float* bias; const float* wsrc;
    if (z == 0)      { src = qin; bias = bq; wsrc = wq; }
    else if (z == 1) { src = kin; bias = bk; wsrc = wk; }
    else             { src = vin; bias = bv; wsrc = wv; }

    const int hp   = blockIdx.y;
    const int g    = hp >> 1;
    const int ch   = hp & 1;
    const int col0 = ch * 128;
    const int row0 = blockIdx.x * 128;
    const int b    = row0 >> 11;
    const int s0   = row0 & 2047;

    __shared__ char smem[36864];
    auto Ws = (__hip_bfloat16 (*)[72])smem;   // [128][72] W^T tile (18.4 KB)

    const int t    = threadIdx.x;
    const int wid  = t >> 6;
    const int lane = t & 63;
    const int l16  = lane & 15;
    const int quad = lane >> 4;

    f32x4 acc[2][8];
    #pragma unroll
    for (int mt = 0; mt < 2; ++mt)
        #pragma unroll
        for (int nt = 0; nt < 8; ++nt) acc[mt][nt] = (f32x4){0.f,0.f,0.f,0.f};

    const float* wg = wsrc + (size_t)g*65536;   // W[g][k][n], k,n = 0..255
    // per-mt A row base for this lane (wave-private rows, v3-verified)
    const float* arow0 = src + (size_t)(row0 + wid*32 +      l16)*CC + g*256;
    const float* arow1 = src + (size_t)(row0 + wid*32 + 16 + l16)*CC + g*256;

    for (int kt = 0; kt < 4; ++kt) {
        // stage W^T tile for this kt: fp32 [64k][128n] -> bf16 Ws[n][k]
        #pragma unroll
        for (int j = 0; j < 8; ++j) {
            int idx = t + j*256;           // 0..2047 float4s
            int row = idx >> 5;            // k_local 0..63
            int n0  = (idx & 31) * 4;      // 0..124
            float4 f = *(const float4*)&wg[(size_t)(kt*64 + row)*256 + col0 + n0];
            Ws[n0+0][row] = __float2bfloat16(f.x);
            Ws[n0+1][row] = __float2bfloat16(f.y);
            Ws[n0+2][row] = __float2bfloat16(f.z);
            Ws[n0+3][row] = __float2bfloat16(f.w);
        }
        __syncthreads();
        #pragma unroll
        for (int kss = 0; kss < 2; ++kss) {
            const int c0 = kt*64 + kss*32 + quad*8;
            bf16x8 af[2];
            #pragma unroll
            for (int mt = 0; mt < 2; ++mt) {
                const float* p = (mt == 0 ? arow0 : arow1) + c0;
                float4 f0 = *(const float4*)p;
                float4 f1 = *(const float4*)(p + 4);
                union { __hip_bfloat16 hh[8]; bf16x8 v; } pk;
                pk.hh[0] = __float2bfloat16(f0.x);
                pk.hh[1] = __float2bfloat16(f0.y);
                pk.hh[2] = __float2bfloat16(f0.z);
                pk.hh[3] = __float2bfloat16(f0.w);
                pk.hh[4] = __float2bfloat16(f1.x);
                pk.hh[5] = __float2bfloat16(f1.y);
                pk.hh[6] = __float2bfloat16(f1.z);
                pk.hh[7] = __float2bfloat16(f1.w);
                af[mt] = pk.v;
            }
            bf16x8 wf[8];
            #pragma unroll
            for (int nt = 0; nt < 8; ++nt)
                wf[nt] = *(const bf16x8*)&Ws[nt*16 + l16][kss*32 + quad*8];
            #pragma unroll
            for (int mt = 0; mt < 2; ++mt)
                #pragma unroll
                for (int nt = 0; nt < 8; ++nt)
                    acc[mt][nt] = mfma16(af[mt], wf[nt], acc[mt][nt]);
        }
        __syncthreads();   // all waves done with Ws before restage/epilogue
    }

    float bval[8];
    #pragma unroll
    for (int nt = 0; nt < 8; ++nt) bval[nt] = bias[g*256 + col0 + nt*16 + l16];

    if (z < 2) {
        const float scale = (z == 0) ? QSC : 1.0f;
        auto Ot = (__hip_bfloat16 (*)[136])smem;
        #pragma unroll
        for (int mt = 0; mt < 2; ++mt)
            #pragma unroll
            for (int nt = 0; nt < 8; ++nt)
                #pragma unroll
                for (int r = 0; r < 4; ++r)
                    Ot[wid*32 + mt*16 + quad*4 + r][nt*16 + l16] =
                        __float2bfloat16((acc[mt][nt][r] + bval[nt]) * scale);
        __syncthreads();
        __hip_bfloat16* base = (z == 0) ? qs : ks_;
        #pragma unroll
        for (int j = 0; j < 8; ++j) {
            int f = wid + j*4;
            int hl = f >> 4, t16l = (f >> 1) & 7, kcs = f & 1;
            uint4 v = *(const uint4*)&Ot[t16l*16 + l16][hl*64 + kcs*32 + quad*8];
            int h = hp*2 + hl;
            int t16g = (s0 >> 4) + t16l;
            *(uint4*)&base[((size_t)(b*HH + h) << 17)
                           + ((size_t)(t16g*2 + kcs) << 9) + lane*8] = v;
        }
    } else {
        auto Vl = (__hip_bfloat16 (*)[136])smem;
        #pragma unroll
        for (int mt = 0; mt < 2; ++mt)
            #pragma unroll
            for (int nt = 0; nt < 8; ++nt) {
                union { __hip_bfloat16 hh[4]; uint2 u; } pk;
                #pragma unroll
                for (int r = 0; r < 4; ++r)
                    pk.hh[r] = __float2bfloat16(acc[mt][nt][r] + bval[nt]);
                *(uint2*)&Vl[nt*16 + l16][wid*32 + mt*16 + quad*4] = pk.u;
            }
        __syncthreads();
        const int kc0 = s0 >> 5;
        #pragma unroll
        for (int j = 0; j < 8; ++j) {
            int f = wid + j*4;
            int hl = f >> 4, dt = (f >> 2) & 3, kcl = f & 3;
            uint4 v = *(const uint4*)&Vl[hl*64 + dt*16 + l16][kcl*32 + quad*8];
            int h = hp*2 + hl;
            *(uint4*)&vs[((size_t)(b*HH + h) << 17)
                         + ((size_t)(dt*64 + kc0 + kcl) << 9) + lane*8] = v;
        }
    }
}

// ---------------------------------------------------------------------------
// Barrier-free-loop MFMA flash attention — EXACT R4 body (measured 50.6/
// 49.6/49.1; split halves ~25 each in R12). Split REVERTED (cost ~4us with
// no new info beyond the fill discovery): single 1024-block dispatch.
// Block = 4 waves over ONE 64-query tile; wave w owns key quarter
// [w*512, w*512+512) = 8 iters x 64 keys. LDS = Ps unioned with epilogue
// combine buffer -> 37.4 KB. (256,2): R2/R8 lesson, caps below ~176 spill.
// XCD swizzle: all 32 q-tiles of a (b,h) on XCD bh%8 (FETCH 69.7->12.4 MB).
// Combine: waves 1,3 dump U,L; 0,2 accumulate; 2 re-dumps; 0 finalizes.
// ---------------------------------------------------------------------------
__global__ __launch_bounds__(256, 2) void attn_mfma(
    const __hip_bfloat16* __restrict__ qs, const __hip_bfloat16* __restrict__ ks_,
    const __hip_bfloat16* __restrict__ vs, float* __restrict__ out)
{
    const int d   = blockIdx.x;
    const int xcd = d & 7;
    const int s   = d >> 3;
    const int qt  = s & 31;              // 0..31 (64-query tile)
    const int bh  = (s >> 5) * 8 + xcd;  // 0..31
    const int h   = bh & 15;
    const int b   = bh >> 4;

    __shared__ char smem[37376];
    auto Ps = (__hip_bfloat16 (*)[64][72])smem;   // [4][64][72] main loop
    auto Ub = (float (*)[64][68])smem;            // [2][64][68] epilogue union
    float* Lb = (float*)(smem + 36864);           // [2][64]

    const int t    = threadIdx.x;
    const int wid  = t >> 6;     // key quarter 0..3
    const int lane = t & 63;
    const int l16  = lane & 15;
    const int quad = lane >> 4;

    const __hip_bfloat16* qb = qs  + ((size_t)bh << 17);
    const __hip_bfloat16* kb = ks_ + ((size_t)bh << 17);
    const __hip_bfloat16* vb = vs  + ((size_t)bh << 17);

    const bf16x8 onesv = (bf16x8){16256,16256,16256,16256,
                                  16256,16256,16256,16256};   // bf16 1.0 x8

    bf16x8 qf[4][2];
    #pragma unroll
    for (int mt = 0; mt < 4; ++mt)
        #pragma unroll
        for (int kss = 0; kss < 2; ++kss)
            qf[mt][kss] = *(const bf16x8*)(qb +
                ((size_t)((qt*4 + mt)*2 + kss) << 9) + lane*8);

    f32x4 O[4][4];
    f32x4 Lfrag[4];
    #pragma unroll
    for (int mt = 0; mt < 4; ++mt) {
        Lfrag[mt] = (f32x4){0.f,0.f,0.f,0.f};
        #pragma unroll
        for (int dt = 0; dt < 4; ++dt) O[mt][dt] = (f32x4){0.f,0.f,0.f,0.f};
    }

    bf16x8 kf[4][2];
    #pragma unroll
    for (int nt = 0; nt < 4; ++nt)
        #pragma unroll
        for (int kss = 0; kss < 2; ++kss)
            kf[nt][kss] = *(const bf16x8*)(kb +
                ((size_t)((wid*32 + nt)*2 + kss) << 9) + lane*8);

    for (int kt = 0; kt < 8; ++kt) {
        bf16x8 vf[4][2];
        #pragma unroll
        for (int dt = 0; dt < 4; ++dt)
            #pragma unroll
            for (int kss = 0; kss < 2; ++kss)
                vf[dt][kss] = *(const bf16x8*)(vb +
                    ((size_t)(dt*64 + wid*16 + kt*2 + kss) << 9) + lane*8);

        #pragma unroll
        for (int nt = 0; nt < 4; ++nt) {
            f32x4 st[4];
            #pragma unroll
            for (int mt = 0; mt < 4; ++mt) {
                f32x4 z = (f32x4){0.f,0.f,0.f,0.f};
                z = mfma16(kf[nt][0], qf[mt][0], z);
                st[mt] = mfma16(kf[nt][1], qf[mt][1], z);
            }
            #pragma unroll
            for (int mt = 0; mt < 4; ++mt) {
                float2 e0, e1;
                e0.x = __builtin_amdgcn_exp2f(st[mt][0]);
                e0.y = __builtin_amdgcn_exp2f(st[mt][1]);
                e1.x = __builtin_amdgcn_exp2f(st[mt][2]);
                e1.y = __builtin_amdgcn_exp2f(st[mt][3]);
                union { __hip_bfloat162 h2[2]; uint2 u; } pk;
                pk.h2[0] = __float22bfloat162_rn(e0);
                pk.h2[1] = __float22bfloat162_rn(e1);
                *(uint2*)&Ps[wid][mt*16 + l16][nt*16 + quad*4] = pk.u;
            }
        }

        if (kt + 1 < 8) {
            #pragma unroll
            for (int nt = 0; nt < 4; ++nt)
                #pragma unroll
                for (int kss = 0; kss < 2; ++kss)
                    kf[nt][kss] = *(const bf16x8*)(kb +
                        ((size_t)((wid*32 + (kt+1)*4 + nt)*2 + kss) << 9) + lane*8);
        }

        #pragma unroll
        for (int kss = 0; kss < 2; ++kss) {
            bf16x8 pf[4];
            #pragma unroll
            for (int mt = 0; mt < 4; ++mt)
                pf[mt] = *(const bf16x8*)&Ps[wid][mt*16 + l16][kss*32 + quad*8];
            #pragma unroll
            for (int mt = 0; mt < 4; ++mt) {
                Lfrag[mt] = mfma16(onesv, pf[mt], Lfrag[mt]);
                #pragma unroll
                for (int dt = 0; dt < 4; ++dt)
                    O[mt][dt] = mfma16(vf[dt][kss], pf[mt], O[mt][dt]);
            }
        }
    }

    // ---- 4-way combine tree (Ps memory reused as Ub/Lb) ----
    __syncthreads();
    if (wid & 1) {
        const int half = wid >> 1;
        #pragma unroll
        for (int mt = 0; mt < 4; ++mt) {
            if (quad == 0) Lb[half*64 + mt*16 + l16] = Lfrag[mt][0];
            #pragma unroll
            for (int dt = 0; dt < 4; ++dt) {
                float4 u4;
                u4.x = O[mt][dt][0]; u4.y = O[mt][dt][1];
                u4.z = O[mt][dt][2]; u4.w = O[mt][dt][3];
                *(float4*)&Ub[half][mt*16 + l16][dt*16 + quad*4] = u4;
            }
        }
    }
    __syncthreads();
    if (!(wid & 1)) {
        const int half = wid >> 1;
        #pragma unroll
        for (int mt = 0; mt < 4; ++mt) {
            Lfrag[mt][0] += Lb[half*64 + mt*16 + l16];
            #pragma unroll
            for (int dt = 0; dt < 4; ++dt) {
                float4 u4 = *(const float4*)&Ub[half][mt*16 + l16][dt*16 + quad*4];
                O[mt][dt][0] += u4.x; O[mt][dt][1] += u4.y;
                O[mt][dt][2] += u4.z; O[mt][dt][3] += u4.w;
            }
        }
    }
    if (wid == 2) {
        #pragma unroll
        for (int mt = 0; mt < 4; ++mt) {
            if (quad == 0) Lb[64 + mt*16 + l16] = Lfrag[mt][0];
            #pragma unroll
            for (int dt = 0; dt < 4; ++dt) {
                float4 u4;
                u4.x = O[mt][dt][0]; u4.y = O[mt][dt][1];
                u4.z = O[mt][dt][2]; u4.w = O[mt][dt][3];
                *(float4*)&Ub[1][mt*16 + l16][dt*16 + quad*4] = u4;
            }
        }
    }
    __syncthreads();
    if (wid == 0) {
        #pragma unroll
        for (int mt = 0; mt < 4; ++mt) {
            const float inv = 1.0f /
                (1.0f + Lfrag[mt][0] + Lb[64 + mt*16 + l16]);
            const size_t row = (size_t)b*SS + qt*64 + mt*16 + l16;
            #pragma unroll
            for (int dt = 0; dt < 4; ++dt) {
                float4 u4 = *(const float4*)&Ub[1][mt*16 + l16][dt*16 + quad*4];
                float4 o4;
                o4.x = (O[mt][dt][0] + u4.x) * inv;
                o4.y = (O[mt][dt][1] + u4.y) * inv;
                o4.z = (O[mt][dt][2] + u4.z) * inv;
                o4.w = (O[mt][dt][3] + u4.w) * inv;
                *(float4*)&out[row*CC + h*DDIM + dt*16 + quad*4] = o4;
            }
        }
    }
}

extern "C" void kernel_launch(void* const* d_in, const int* in_sizes, int n_in,
                              void* d_out, int out_size, void* d_ws, size_t ws_size,
                              hipStream_t stream) {
    (void)in_sizes; (void)n_in; (void)out_size; (void)ws_size;
    const float* qin = (const float*)d_in[0];
    const float* kin = (const float*)d_in[1];
    const float* vin = (const float*)d_in[2];
    const float* wq  = (const float*)d_in[3];
    const float* wk  = (const float*)d_in[4];
    const float* wv  = (const float*)d_in[5];
    const float* bq  = (const float*)d_in[6];
    const float* bk  = (const float*)d_in[7];
    const float* bv  = (const float*)d_in[8];

    // ws: qs/ks/vs swizzled bf16 (8 MB each); wt eliminated (W fused into proj)
    char* w0 = (char*)d_ws;
    __hip_bfloat16* qs = (__hip_bfloat16*)(w0);
    __hip_bfloat16* ks = (__hip_bfloat16*)(w0 + 8388608);
    __hip_bfloat16* vs = (__hip_bfloat16*)(w0 + 16777216);
    float* out = (float*)d_out;

    proj_mfma<<<dim3(32, 8, 3), 256, 0, stream>>>(
        qin, kin, vin, wq, wk, wv, bq, bk, bv, qs, ks, vs);
    attn_mfma<<<dim3(1024, 1, 1), 256, 0, stream>>>(qs, ks, vs, out);
}

// Round 16
// 159.354 us; speedup vs baseline: 1.0756x; 1.0756x over previous
//
#include <hip/hip_runtime.h>
#include <hip/hip_bf16.h>

// Problem constants
#define BB 2
#define SS 2048
#define CC 1024
#define HH 16
#define DDIM 64
#define NROWS (BB*SS)   // 4096

// q pre-scale: (1/sqrt(64)) / ln2  -> scores in log2 units, exp2 == exp
#define QSC 0.18033688011112042f

typedef __attribute__((ext_vector_type(8))) short bf16x8;   // 8 bf16 = 4 VGPR
typedef __attribute__((ext_vector_type(4))) float f32x4;

__device__ __forceinline__ f32x4 mfma16(bf16x8 a, bf16x8 b, f32x4 c) {
    return __builtin_amdgcn_mfma_f32_16x16x32_bf16(a, b, c, 0, 0, 0);
}

// ---------------------------------------------------------------------------
// prep_wt v2 (R7-verified, session-best config): W fp32 [g][k][n] -> bf16
// W^T in per-lane FRAGMENT order: wt[zg][ch][kt][kss][nt][lane][8],
//   elem j = W[g][kt*64+kss*32+quad*8+j][ch*128+nt*16+l16]
// so proj loads B-fragments straight from global (coalesced 16B/lane).
// R15 lesson: fusing this into proj (per-block re-staging) REGRESSED +8us
// (96MB extra L2 W-reads + 2 barriers/kt x 768 blocks > 1 dispatch cost).
// ---------------------------------------------------------------------------
__global__ __launch_bounds__(256) void prep_wt(
    const float* __restrict__ wq, const float* __restrict__ wk,
    const float* __restrict__ wv, __hip_bfloat16* __restrict__ wt)
{
    const float* w = blockIdx.z == 0 ? wq : blockIdx.z == 1 ? wk : wv;
    const int g   = blockIdx.y;
    const int kt  = blockIdx.x >> 2;
    const int ntb = blockIdx.x & 3;
    __shared__ __hip_bfloat16 Ls[64][72];   // [n_local][k_local]
    const int t = threadIdx.x;
    #pragma unroll
    for (int j = 0; j < 4; ++j) {
        int f4 = t + j*256;
        int row = f4 >> 4, n0 = (f4 & 15) * 4;
        float4 f = *(const float4*)&w[(size_t)g*65536 + (size_t)(kt*64+row)*256
                                      + ntb*64 + n0];
        Ls[n0+0][row] = __float2bfloat16(f.x);
        Ls[n0+1][row] = __float2bfloat16(f.y);
        Ls[n0+2][row] = __float2bfloat16(f.z);
        Ls[n0+3][row] = __float2bfloat16(f.w);
    }
    __syncthreads();
    const int zg = blockIdx.z*4 + g;
    const int ch = ntb >> 1;
    #pragma unroll
    for (int j = 0; j < 2; ++j) {
        int u    = t + j*256;          // 512 uint4 writes
        int n16g = u >> 7;             // 0..3
        int kss  = (u >> 6) & 1;
        int lane = u & 63;
        int l16  = lane & 15, quad = lane >> 4;
        int nt   = (ntb & 1)*4 + n16g; // 0..7
        size_t frag = (((size_t)(zg*2 + ch)*4 + kt)*2 + kss)*8 + nt;
        *(uint4*)&wt[frag*512 + lane*8] =
            *(const uint4*)&Ls[n16g*16 + l16][kss*32 + quad*8];
    }
}

// ---------------------------------------------------------------------------
// MFMA grouped projection v2 (R7-verified, session-best config, 160.6 total).
// W fragments direct from global (fragment-order wt, L2-resident);
// A double-buffered in LDS; T14 split staging; one barrier per kt.
// Emits attention swizzle:
//   qs/ks per (b,h): [t16][kcs][lane(l16=seq,quad*8=d)][8]
//   vs    per (b,h): [dt][kc][lane(l16=d,quad*8=key)][8]
// grid (32, 8, 3) = 768 blocks.
// ---------------------------------------------------------------------------
__global__ __launch_bounds__(256, 2) void proj_mfma(
    const float* __restrict__ qin, const float* __restrict__ kin,
    const float* __restrict__ vin,
    const __hip_bfloat16* __restrict__ wt,
    const float* __restrict__ bq, const float* __restrict__ bk,
    const float* __restrict__ bv,
    __hip_bfloat16* __restrict__ qs, __hip_bfloat16* __restrict__ ks_,
    __hip_bfloat16* __restrict__ vs)
{
    const int z = blockIdx.z;
    const float* src; const float* bias;
    if (z == 0)      { src = qin; bias = bq; }
    else if (z == 1) { src = kin; bias = bk; }
    else             { src = vin; bias = bv; }

    const int hp   = blockIdx.y;
    const int g    = hp >> 1;
    const int ch   = hp & 1;
    const int col0 = ch * 128;
    const int row0 = blockIdx.x * 128;
    const int b    = row0 >> 11;
    const int s0   = row0 & 2047;

    __shared__ char smem[36864];
    auto As = (__hip_bfloat16 (*)[128][72])smem;   // [2][128][72] dbuf A

    const int t    = threadIdx.x;
    const int wid  = t >> 6;
    const int lane = t & 63;
    const int l16  = lane & 15;
    const int quad = lane >> 4;

    f32x4 acc[2][8];
    #pragma unroll
    for (int mt = 0; mt < 2; ++mt)
        #pragma unroll
        for (int nt = 0; nt < 8; ++nt) acc[mt][nt] = (f32x4){0.f,0.f,0.f,0.f};

    // fragment base for this (zg, ch): 64 fragments of 512 elems
    const __hip_bfloat16* wfb = wt + ((size_t)((z*4 + g)*2 + ch) << 15);

    // stage A tile kt=0 into buf 0
    #pragma unroll
    for (int j = 0; j < 8; ++j) {
        int idx = t + j*256;
        int row = idx >> 4, c4 = (idx & 15) * 4;
        float4 f = *(const float4*)&src[(size_t)(row0 + row)*CC + g*256 + c4];
        union { __hip_bfloat16 hh[4]; uint2 u; } pk;
        pk.hh[0] = __float2bfloat16(f.x); pk.hh[1] = __float2bfloat16(f.y);
        pk.hh[2] = __float2bfloat16(f.z); pk.hh[3] = __float2bfloat16(f.w);
        *(uint2*)&As[0][row][c4] = pk.u;
    }
    __syncthreads();

    for (int kt = 0; kt < 4; ++kt) {
        const int cur = kt & 1;
        // issue A(kt+1) loads early (latency hides under MFMA below)
        float4 fr[8];
        if (kt < 3) {
            #pragma unroll
            for (int j = 0; j < 8; ++j) {
                int idx = t + j*256;
                int row = idx >> 4, c4 = (idx & 15) * 4;
                fr[j] = *(const float4*)&src[(size_t)(row0 + row)*CC + g*256
                                             + (kt+1)*64 + c4];
            }
        }
        // MFMA on buf cur; W fragments straight from global (L2-hot)
        #pragma unroll
        for (int kss = 0; kss < 2; ++kss) {
            bf16x8 af[2], wf[8];
            #pragma unroll
            for (int mt = 0; mt < 2; ++mt)
                af[mt] = *(const bf16x8*)
                    &As[cur][wid*32 + mt*16 + l16][kss*32 + quad*8];
            #pragma unroll
            for (int nt = 0; nt < 8; ++nt)
                wf[nt] = *(const bf16x8*)
                    (wfb + (((size_t)(kt*2 + kss)*8 + nt) << 9) + lane*8);
            #pragma unroll
            for (int mt = 0; mt < 2; ++mt)
                #pragma unroll
                for (int nt = 0; nt < 8; ++nt)
                    acc[mt][nt] = mfma16(af[mt], wf[nt], acc[mt][nt]);
        }
        // convert + write A(kt+1) into the other buffer
        if (kt < 3) {
            #pragma unroll
            for (int j = 0; j < 8; ++j) {
                int idx = t + j*256;
                int row = idx >> 4, c4 = (idx & 15) * 4;
                union { __hip_bfloat16 hh[4]; uint2 u; } pk;
                pk.hh[0] = __float2bfloat16(fr[j].x);
                pk.hh[1] = __float2bfloat16(fr[j].y);
                pk.hh[2] = __float2bfloat16(fr[j].z);
                pk.hh[3] = __float2bfloat16(fr[j].w);
                *(uint2*)&As[cur^1][row][c4] = pk.u;
            }
        }
        __syncthreads();
    }

    float bval[8];
    #pragma unroll
    for (int nt = 0; nt < 8; ++nt) bval[nt] = bias[g*256 + col0 + nt*16 + l16];

    if (z < 2) {
        const float scale = (z == 0) ? QSC : 1.0f;
        auto Ot = (__hip_bfloat16 (*)[136])smem;
        #pragma unroll
        for (int mt = 0; mt < 2; ++mt)
            #pragma unroll
            for (int nt = 0; nt < 8; ++nt)
                #pragma unroll
                for (int r = 0; r < 4; ++r)
                    Ot[wid*32 + mt*16 + quad*4 + r][nt*16 + l16] =
                        __float2bfloat16((acc[mt][nt][r] + bval[nt]) * scale);
        __syncthreads();
        __hip_bfloat16* base = (z == 0) ? qs : ks_;
        #pragma unroll
        for (int j = 0; j < 8; ++j) {
            int f = wid + j*4;
            int hl = f >> 4, t16l = (f >> 1) & 7, kcs = f & 1;
            uint4 v = *(const uint4*)&Ot[t16l*16 + l16][hl*64 + kcs*32 + quad*8];
            int h = hp*2 + hl;
            int t16g = (s0 >> 4) + t16l;
            *(uint4*)&base[((size_t)(b*HH + h) << 17)
                           + ((size_t)(t16g*2 + kcs) << 9) + lane*8] = v;
        }
    } else {
        auto Vl = (__hip_bfloat16 (*)[136])smem;
        #pragma unroll
        for (int mt = 0; mt < 2; ++mt)
            #pragma unroll
            for (int nt = 0; nt < 8; ++nt) {
                union { __hip_bfloat16 hh[4]; uint2 u; } pk;
                #pragma unroll
                for (int r = 0; r < 4; ++r)
                    pk.hh[r] = __float2bfloat16(acc[mt][nt][r] + bval[nt]);
                *(uint2*)&Vl[nt*16 + l16][wid*32 + mt*16 + quad*4] = pk.u;
            }
        __syncthreads();
        const int kc0 = s0 >> 5;
        #pragma unroll
        for (int j = 0; j < 8; ++j) {
            int f = wid + j*4;
            int hl = f >> 4, dt = (f >> 2) & 3, kcl = f & 3;
            uint4 v = *(const uint4*)&Vl[hl*64 + dt*16 + l16][kcl*32 + quad*8];
            int h = hp*2 + hl;
            *(uint4*)&vs[((size_t)(b*HH + h) << 17)
                         + ((size_t)(dt*64 + kc0 + kcl) << 9) + lane*8] = v;
        }
    }
}

// ---------------------------------------------------------------------------
// Barrier-free-loop MFMA flash attention — EXACT R4 body (measured 50.6/
// 49.6/49.1/51.6 across four sessions; schedule-insensitive at its
// register-pinned 2 waves/SIMD occupancy: caps spill (R2/R8), traffic cuts
// don't help (R4), pipelining neutral (R5)). Latency-bound plateau.
// Block = 4 waves over ONE 64-query tile; wave w owns key quarter
// [w*512, w*512+512) = 8 iters x 64 keys. LDS = Ps unioned with epilogue
// combine buffer -> 37.4 KB. grid 1024 blocks.
// XCD swizzle: all 32 q-tiles of a (b,h) on XCD bh%8 (FETCH 69.7->12.4 MB).
// Combine: waves 1,3 dump U,L; 0,2 accumulate; 2 re-dumps; 0 finalizes.
// ---------------------------------------------------------------------------
__global__ __launch_bounds__(256, 2) void attn_mfma(
    const __hip_bfloat16* __restrict__ qs, const __hip_bfloat16* __restrict__ ks_,
    const __hip_bfloat16* __restrict__ vs, float* __restrict__ out)
{
    const int d   = blockIdx.x;
    const int xcd = d & 7;
    const int s   = d >> 3;
    const int qt  = s & 31;              // 0..31 (64-query tile)
    const int bh  = (s >> 5) * 8 + xcd;  // 0..31
    const int h   = bh & 15;
    const int b   = bh >> 4;

    __shared__ char smem[37376];
    auto Ps = (__hip_bfloat16 (*)[64][72])smem;   // [4][64][72] main loop
    auto Ub = (float (*)[64][68])smem;            // [2][64][68] epilogue union
    float* Lb = (float*)(smem + 36864);           // [2][64]

    const int t    = threadIdx.x;
    const int wid  = t >> 6;     // key quarter 0..3
    const int lane = t & 63;
    const int l16  = lane & 15;
    const int quad = lane >> 4;

    const __hip_bfloat16* qb = qs  + ((size_t)bh << 17);
    const __hip_bfloat16* kb = ks_ + ((size_t)bh << 17);
    const __hip_bfloat16* vb = vs  + ((size_t)bh << 17);

    const bf16x8 onesv = (bf16x8){16256,16256,16256,16256,
                                  16256,16256,16256,16256};   // bf16 1.0 x8

    bf16x8 qf[4][2];
    #pragma unroll
    for (int mt = 0; mt < 4; ++mt)
        #pragma unroll
        for (int kss = 0; kss < 2; ++kss)
            qf[mt][kss] = *(const bf16x8*)(qb +
                ((size_t)((qt*4 + mt)*2 + kss) << 9) + lane*8);

    f32x4 O[4][4];
    f32x4 Lfrag[4];
    #pragma unroll
    for (int mt = 0; mt < 4; ++mt) {
        Lfrag[mt] = (f32x4){0.f,0.f,0.f,0.f};
        #pragma unroll
        for (int dt = 0; dt < 4; ++dt) O[mt][dt] = (f32x4){0.f,0.f,0.f,0.f};
    }

    bf16x8 kf[4][2];
    #pragma unroll
    for (int nt = 0; nt < 4; ++nt)
        #pragma unroll
        for (int kss = 0; kss < 2; ++kss)
            kf[nt][kss] = *(const bf16x8*)(kb +
                ((size_t)((wid*32 + nt)*2 + kss) << 9) + lane*8);

    for (int kt = 0; kt < 8; ++kt) {
        bf16x8 vf[4][2];
        #pragma unroll
        for (int dt = 0; dt < 4; ++dt)
            #pragma unroll
            for (int kss = 0; kss < 2; ++kss)
                vf[dt][kss] = *(const bf16x8*)(vb +
                    ((size_t)(dt*64 + wid*16 + kt*2 + kss) << 9) + lane*8);

        #pragma unroll
        for (int nt = 0; nt < 4; ++nt) {
            f32x4 st[4];
            #pragma unroll
            for (int mt = 0; mt < 4; ++mt) {
                f32x4 z = (f32x4){0.f,0.f,0.f,0.f};
                z = mfma16(kf[nt][0], qf[mt][0], z);
                st[mt] = mfma16(kf[nt][1], qf[mt][1], z);
            }
            #pragma unroll
            for (int mt = 0; mt < 4; ++mt) {
                float2 e0, e1;
                e0.x = __builtin_amdgcn_exp2f(st[mt][0]);
                e0.y = __builtin_amdgcn_exp2f(st[mt][1]);
                e1.x = __builtin_amdgcn_exp2f(st[mt][2]);
                e1.y = __builtin_amdgcn_exp2f(st[mt][3]);
                union { __hip_bfloat162 h2[2]; uint2 u; } pk;
                pk.h2[0] = __float22bfloat162_rn(e0);
                pk.h2[1] = __float22bfloat162_rn(e1);
                *(uint2*)&Ps[wid][mt*16 + l16][nt*16 + quad*4] = pk.u;
            }
        }

        if (kt + 1 < 8) {
            #pragma unroll
            for (int nt = 0; nt < 4; ++nt)
                #pragma unroll
                for (int kss = 0; kss < 2; ++kss)
                    kf[nt][kss] = *(const bf16x8*)(kb +
                        ((size_t)((wid*32 + (kt+1)*4 + nt)*2 + kss) << 9) + lane*8);
        }

        #pragma unroll
        for (int kss = 0; kss < 2; ++kss) {
            bf16x8 pf[4];
            #pragma unroll
            for (int mt = 0; mt < 4; ++mt)
                pf[mt] = *(const bf16x8*)&Ps[wid][mt*16 + l16][kss*32 + quad*8];
            #pragma unroll
            for (int mt = 0; mt < 4; ++mt) {
                Lfrag[mt] = mfma16(onesv, pf[mt], Lfrag[mt]);
                #pragma unroll
                for (int dt = 0; dt < 4; ++dt)
                    O[mt][dt] = mfma16(vf[dt][kss], pf[mt], O[mt][dt]);
            }
        }
    }

    // ---- 4-way combine tree (Ps memory reused as Ub/Lb) ----
    __syncthreads();
    if (wid & 1) {
        const int half = wid >> 1;
        #pragma unroll
        for (int mt = 0; mt < 4; ++mt) {
            if (quad == 0) Lb[half*64 + mt*16 + l16] = Lfrag[mt][0];
            #pragma unroll
            for (int dt = 0; dt < 4; ++dt) {
                float4 u4;
                u4.x = O[mt][dt][0]; u4.y = O[mt][dt][1];
                u4.z = O[mt][dt][2]; u4.w = O[mt][dt][3];
                *(float4*)&Ub[half][mt*16 + l16][dt*16 + quad*4] = u4;
            }
        }
    }
    __syncthreads();
    if (!(wid & 1)) {
        const int half = wid >> 1;
        #pragma unroll
        for (int mt = 0; mt < 4; ++mt) {
            Lfrag[mt][0] += Lb[half*64 + mt*16 + l16];
            #pragma unroll
            for (int dt = 0; dt < 4; ++dt) {
                float4 u4 = *(const float4*)&Ub[half][mt*16 + l16][dt*16 + quad*4];
                O[mt][dt][0] += u4.x; O[mt][dt][1] += u4.y;
                O[mt][dt][2] += u4.z; O[mt][dt][3] += u4.w;
            }
        }
    }
    if (wid == 2) {
        #pragma unroll
        for (int mt = 0; mt < 4; ++mt) {
            if (quad == 0) Lb[64 + mt*16 + l16] = Lfrag[mt][0];
            #pragma unroll
            for (int dt = 0; dt < 4; ++dt) {
                float4 u4;
                u4.x = O[mt][dt][0]; u4.y = O[mt][dt][1];
                u4.z = O[mt][dt][2]; u4.w = O[mt][dt][3];
                *(float4*)&Ub[1][mt*16 + l16][dt*16 + quad*4] = u4;
            }
        }
    }
    __syncthreads();
    if (wid == 0) {
        #pragma unroll
        for (int mt = 0; mt < 4; ++mt) {
            const float inv = 1.0f /
                (1.0f + Lfrag[mt][0] + Lb[64 + mt*16 + l16]);
            const size_t row = (size_t)b*SS + qt*64 + mt*16 + l16;
            #pragma unroll
            for (int dt = 0; dt < 4; ++dt) {
                float4 u4 = *(const float4*)&Ub[1][mt*16 + l16][dt*16 + quad*4];
                float4 o4;
                o4.x = (O[mt][dt][0] + u4.x) * inv;
                o4.y = (O[mt][dt][1] + u4.y) * inv;
                o4.z = (O[mt][dt][2] + u4.z) * inv;
                o4.w = (O[mt][dt][3] + u4.w) * inv;
                *(float4*)&out[row*CC + h*DDIM + dt*16 + quad*4] = o4;
            }
        }
    }
}

extern "C" void kernel_launch(void* const* d_in, const int* in_sizes, int n_in,
                              void* d_out, int out_size, void* d_ws, size_t ws_size,
                              hipStream_t stream) {
    (void)in_sizes; (void)n_in; (void)out_size; (void)ws_size;
    const float* qin = (const float*)d_in[0];
    const float* kin = (const float*)d_in[1];
    const float* vin = (const float*)d_in[2];
    const float* wq  = (const float*)d_in[3];
    const float* wk  = (const float*)d_in[4];
    const float* wv  = (const float*)d_in[5];
    const float* bq  = (const float*)d_in[6];
    const float* bk  = (const float*)d_in[7];
    const float* bv  = (const float*)d_in[8];

    // ws: qs/ks/vs swizzled bf16 (8 MB each) + wt 1.5 MB (fragment order)
    char* w0 = (char*)d_ws;
    __hip_bfloat16* qs = (__hip_bfloat16*)(w0);
    __hip_bfloat16* ks = (__hip_bfloat16*)(w0 + 8388608);
    __hip_bfloat16* vs = (__hip_bfloat16*)(w0 + 16777216);
    __hip_bfloat16* wt = (__hip_bfloat16*)(w0 + 25165824);
    float* out = (float*)d_out;

    prep_wt<<<dim3(16, 4, 3), 256, 0, stream>>>(wq, wk, wv, wt);
    proj_mfma<<<dim3(32, 8, 3), 256, 0, stream>>>(
        qin, kin, vin, wt, bq, bk, bv, qs, ks, vs);
    attn_mfma<<<dim3(1024, 1, 1), 256, 0, stream>>>(qs, ks, vs, out);
}